// Round 3
// baseline (1863.037 us; speedup 1.0000x reference)
//
#include <hip/hip_runtime.h>
#include <cstdint>
#include <cstddef>

#define SS 200
#define NV 100001   // V+1

using short8 = __attribute__((ext_vector_type(8))) short;
using f32x4  = __attribute__((ext_vector_type(4))) float;

__device__ __forceinline__ unsigned short f2bf(float f){
  unsigned int x = __float_as_uint(f);
  x += 0x7fffu + ((x >> 16) & 1u);
  return (unsigned short)(x >> 16);
}
__device__ __forceinline__ float sigm(float x){
  return __builtin_amdgcn_rcpf(1.0f + exp2f(x * -1.44269504f));
}

#define MFB(a,b,c) __builtin_amdgcn_mfma_f32_16x16x32_bf16((a),(b),(c),0,0,0)
#define MF8(a,b,c) __builtin_amdgcn_mfma_f32_16x16x32_fp8_fp8((a),(b),(c),0,0,0)

// ---------------- prep: coalesced-read weight swizzle + token transpose -------------
// rb  : rec_kernel bf16 frags  [w(8)][t(8)][kt(8)][lane(64)][j(8)]
// kb8 : kernel fp8 frags       [w(8)][t(8)][kt(2)][lane(64)][j(8)]
// tokT: tokens transposed [s][b]
__global__ void prep_kernel(const int* __restrict__ inp,
                            const float* __restrict__ kern,
                            const float* __restrict__ rec,
                            unsigned short* __restrict__ rb,
                            unsigned char* __restrict__ kb8,
                            int* __restrict__ tokT){
  int idx = blockIdx.x * 256 + threadIdx.x;
  if (idx < 262144){                    // rec: 256 x 1024, coalesced read
    int k = idx >> 10, col = idx & 1023;
    int gg = col >> 8, w = (col >> 5) & 7, hh = (col >> 4) & 1, l15 = col & 15;
    int kt = k >> 5, hi = (k >> 3) & 3, j = k & 7;
    int lane = l15 + (hi << 4);
    int t = gg * 2 + hh;
    rb[(((w*8 + t)*8 + kt) << 9) + lane*8 + j] = f2bf(rec[idx]);
  }
  if (idx < 65536){                     // kernel: 64 x 1024
    int k = idx >> 10, col = idx & 1023;
    int gg = col >> 8, w = (col >> 5) & 7, hh = (col >> 4) & 1, l15 = col & 15;
    int kt = k >> 5, hi = (k >> 3) & 3, j = k & 7;
    int lane = l15 + (hi << 4);
    int t = gg * 2 + hh;
    int p = __builtin_amdgcn_cvt_pk_fp8_f32(kern[idx], 0.0f, 0, false);
    kb8[(((w*8 + t)*2 + kt) << 9) + lane*8 + j] = (unsigned char)(p & 0xff);
  }
  if (idx < 204800){                    // token transpose
    int s = idx >> 10, b = idx & 1023;
    tokT[idx] = inp[b * SS + s];
  }
}

// ---------------- LSTM: 64 blocks x 512 thr (8 waves), 16 batch rows per block ------
// Swapped MFMA: A = weights (M = z), B = h/x (N = batch). D: row=z(l4*4+r), col=batch(l15).
// waves_per_eu(2,2): exactly 2 waves/SIMD (1 block/CU by LDS) -> 256-VGPR budget, no
// spill of the 128-VGPR resident weight set (the allocator heuristic had chosen 128
// and spilled the loop state to scratch -> 20k cyc/step).
// LDS: h[2](16K) | xA[2](2K) | rBl kt4 (64K) | kBl fp8 (64K) | biasL (4K) = 150K
__global__ void __attribute__((amdgpu_flat_work_group_size(512, 512),
                               amdgpu_waves_per_eu(2, 2)))
lstm_kernel(const float* __restrict__ emb,
            const float* __restrict__ bias,
            const unsigned short* __restrict__ rb,
            const unsigned char* __restrict__ kb8,
            const int* __restrict__ tokT,
            float* __restrict__ hout){
  extern __shared__ char smem[];
  char*  const hbuf0 = smem;                    // 2 x 8192
  char*  const xbuf0 = smem + 16384;            // 2 x 1024
  char*  const rBl   = smem + 18432;            // 65536 (rec kt4)
  char*  const kBl   = smem + 83968;            // 65536 (kernel fp8)
  float* const biasL = (float*)(smem + 149504); // 4096
  const int tid  = threadIdx.x;
  const int lane = tid & 63;
  const int w    = tid >> 6;
  const int l15  = lane & 15;
  const int l4   = lane >> 4;
  const int b0   = blockIdx.x << 4;

  #define RBF(t,kt) (*(const short8*)(rb + (((w*8+(t))*8+(kt)) << 9) + (lane<<3)))

  // resident rec frags kt0-3 (128 VGPR)
  short8 Wr[4][8];
  #pragma unroll
  for (int kt = 0; kt < 4; ++kt)
    #pragma unroll
    for (int t = 0; t < 8; ++t) Wr[kt][t] = RBF(t, kt);
  // rec kt4 -> LDS
  #pragma unroll
  for (int t = 0; t < 8; ++t){
    short8 v = RBF(t, 4);
    *(short8*)(rBl + w*8192 + t*1024 + (lane<<4)) = v;
  }
  // kernel fp8 frags -> LDS
  #pragma unroll
  for (int f = 0; f < 16; ++f){
    long v = *(const long*)(kb8 + (w*16 + f)*512 + (lane<<3));
    *(long*)(kBl + w*8192 + f*512 + (lane<<3)) = v;
  }
  for (int i = tid; i < 1024; i += 512) biasL[i] = bias[i];
  *(f32x4*)(hbuf0 + tid*16) = f32x4{0.f,0.f,0.f,0.f};

  // stream buffer: kt5 for step 0
  short8 S[8];
  #pragma unroll
  for (int t = 0; t < 8; ++t) S[t] = RBF(t, 5);

  float c[2][4], hr[2][4];
  #pragma unroll
  for (int hh = 0; hh < 2; ++hh)
    #pragma unroll
    for (int r = 0; r < 4; ++r){ c[hh][r] = 0.f; hr[hh][r] = 0.f; }

  const int row = tid >> 5;        // x-staging role: batch row 0..15
  const int e0  = (tid & 31) << 1; // emb elems e0, e0+1
  __syncthreads();
  {
    int tok0 = tokT[b0 + row];
    float2 xv = *(const float2*)(emb + (size_t)tok0 * 64 + e0);
    int p = __builtin_amdgcn_cvt_pk_fp8_f32(xv.x, xv.y, 0, false);
    int kt = e0 >> 5, lp = row + (((e0 & 31) >> 3) << 4), j = e0 & 7;
    *(unsigned short*)(xbuf0 + kt*512 + lp*8 + j) = (unsigned short)(p & 0xffff);
  }
  __syncthreads();

  #pragma unroll 1
  for (int s = 0; s < SS; ++s){
    char* const hc = hbuf0 + ((s & 1) << 13);
    char* const hn = hbuf0 + (((s & 1) ^ 1) << 13);
    char* const xc = xbuf0 + ((s & 1) << 10);
    char* const xn = xbuf0 + (((s & 1) ^ 1) << 10);

    // mask token (this step) + x prefetch (next step) — issued early
    int tk = tokT[s*1024 + b0 + l15];
    float2 xv = make_float2(0.f, 0.f);
    if (s + 1 < SS){
      int tok_n = tokT[(s+1)*1024 + b0 + row];
      xv = *(const float2*)(emb + (size_t)tok_n * 64 + e0);
    }

    // acc init from bias (broadcast ds_read_b128)
    f32x4 acc[8];
    #pragma unroll
    for (int t = 0; t < 8; ++t){
      int gg = t >> 1, hh = t & 1;
      acc[t] = *(const f32x4*)(biasL + gg*256 + w*32 + hh*16 + (l4<<2));
    }

    // kt5 (S ready from previous step / prologue)
    {
      short8 h5 = *(const short8*)(hc + 5*1024 + (lane<<4));
      #pragma unroll
      for (int t = 0; t < 8; ++t) acc[t] = MFB(S[t], h5, acc[t]);
    }
    #pragma unroll
    for (int t = 0; t < 8; ++t) S[t] = RBF(t, 6);   // issue kt6

    // kt0-3 (VGPR-resident weights) — covers kt6 latency
    #pragma unroll
    for (int kt = 0; kt < 4; ++kt){
      short8 h = *(const short8*)(hc + kt*1024 + (lane<<4));
      #pragma unroll
      for (int t = 0; t < 8; ++t) acc[t] = MFB(Wr[kt][t], h, acc[t]);
    }

    // kt6
    {
      short8 h6 = *(const short8*)(hc + 6*1024 + (lane<<4));
      #pragma unroll
      for (int t = 0; t < 8; ++t) acc[t] = MFB(S[t], h6, acc[t]);
    }
    #pragma unroll
    for (int t = 0; t < 8; ++t) S[t] = RBF(t, 7);   // issue kt7

    // kt4 (LDS) + x0 (fp8) — covers kt7 latency
    {
      short8 h4 = *(const short8*)(hc + 4*1024 + (lane<<4));
      #pragma unroll
      for (int t = 0; t < 8; ++t){
        short8 bw = *(const short8*)(rBl + w*8192 + t*1024 + (lane<<4));
        acc[t] = MFB(bw, h4, acc[t]);
      }
    }
    {
      long ax = *(const long*)(xc + (lane<<3));
      #pragma unroll
      for (int t = 0; t < 8; ++t){
        long bx = *(const long*)(kBl + w*8192 + (t*2)*512 + (lane<<3));
        acc[t] = MF8(bx, ax, acc[t]);
      }
    }

    // kt7
    {
      short8 h7 = *(const short8*)(hc + 7*1024 + (lane<<4));
      #pragma unroll
      for (int t = 0; t < 8; ++t) acc[t] = MFB(S[t], h7, acc[t]);
    }
    #pragma unroll
    for (int t = 0; t < 8; ++t) S[t] = RBF(t, 5);   // issue kt5 for NEXT step

    // x1 (fp8)
    {
      long ax = *(const long*)(xc + 512 + (lane<<3));
      #pragma unroll
      for (int t = 0; t < 8; ++t){
        long bx = *(const long*)(kBl + w*8192 + (t*2+1)*512 + (lane<<3));
        acc[t] = MF8(bx, ax, acc[t]);
      }
    }

    // gates: all-sigmoid LSTM; masked rows keep state; h write packs 4 bf16 -> b64
    #pragma unroll
    for (int hh = 0; hh < 2; ++hh){
      unsigned long long pk = 0ull;
      #pragma unroll
      for (int r = 0; r < 4; ++r){
        float zi = acc[0+hh][r];
        float zf = acc[2+hh][r];
        float zg = acc[4+hh][r];
        float zo = acc[6+hh][r];
        float si = sigm(zi), sf = sigm(zf), sg = sigm(zg), so = sigm(zo);
        float cn = sf * c[hh][r] + si * sg;
        float hv = so * sigm(cn);
        if (tk != 0){ c[hh][r] = cn; hr[hh][r] = hv; }
        pk |= ((unsigned long long)f2bf(hr[hh][r])) << (16*r);
      }
      int lane_a = l15 + ((hh*2 + (l4 >> 1)) << 4);
      *(unsigned long long*)(hn + (w<<10) + lane_a*16 + ((l4 & 1) << 3)) = pk;
    }

    // stage next x (fp8)
    if (s + 1 < SS){
      int p = __builtin_amdgcn_cvt_pk_fp8_f32(xv.x, xv.y, 0, false);
      int kt = e0 >> 5, lp = row + (((e0 & 31) >> 3) << 4), j = e0 & 7;
      *(unsigned short*)(xn + kt*512 + lp*8 + j) = (unsigned short)(p & 0xffff);
    }
    __syncthreads();   // single barrier per step (double-buffered h & x)
  }

  // final h (fp32)
  #pragma unroll
  for (int hh = 0; hh < 2; ++hh){
    *(float4*)(hout + (b0 + l15)*256 + w*32 + hh*16 + (l4<<2)) =
        make_float4(hr[hh][0], hr[hh][1], hr[hh][2], hr[hh][3]);
  }
  #undef RBF
}

// ---------------- dense: out = h @ dense_w + dense_b  (1024x64, K=256) --------------
__global__ void dense_kernel(const float* __restrict__ h,
                             const float* __restrict__ dw,
                             const float* __restrict__ db,
                             float* __restrict__ outv){
  int tid = threadIdx.x;
  int e = tid & 63;
  int b = blockIdx.x * 4 + (tid >> 6);
  const float* hb = h + b * 256;
  float a = db[e];
  #pragma unroll 8
  for (int u = 0; u < 256; ++u) a = fmaf(hb[u], dw[u*64 + e], a);
  outv[b*64 + e] = a;
}

// ---------------- logits: dst = out @ emb.T  (1024 x 100001, K=64, fp32) ------------
// batch split over gridDim.y for occupancy (1564 blocks)
__global__ void __launch_bounds__(256)
logits_kernel(const float* __restrict__ outv,
              const float* __restrict__ emb,
              float* __restrict__ dst){
  int v = blockIdx.x * 256 + threadIdx.x;
  const bool valid = (v < NV);
  const int vs = valid ? v : 0;
  const int bb = blockIdx.y * 256;
  float er[64];
  #pragma unroll
  for (int q = 0; q < 16; ++q){
    float4 tq = *(const float4*)(emb + (size_t)vs * 64 + q*4);
    er[q*4+0] = tq.x; er[q*4+1] = tq.y; er[q*4+2] = tq.z; er[q*4+3] = tq.w;
  }
  for (int b = bb; b < bb + 256; ++b){
    const float* ob = outv + b*64;   // wave-uniform -> scalar loads
    float a0 = 0.f, a1 = 0.f;
    #pragma unroll
    for (int e = 0; e < 64; e += 2){
      a0 = fmaf(ob[e],   er[e],   a0);
      a1 = fmaf(ob[e+1], er[e+1], a1);
    }
    if (valid) dst[(size_t)b * NV + v] = a0 + a1;
  }
}

extern "C" void kernel_launch(void* const* d_in, const int* in_sizes, int n_in,
                              void* d_out, int out_size, void* d_ws, size_t ws_size,
                              hipStream_t stream){
  const int*   inp  = (const int*)  d_in[0];
  const float* emb  = (const float*)d_in[1];
  const float* kern = (const float*)d_in[2];
  const float* rec  = (const float*)d_in[3];
  const float* bias = (const float*)d_in[4];
  const float* dw   = (const float*)d_in[5];
  const float* db   = (const float*)d_in[6];
  float* dst = (float*)d_out;
  char* ws = (char*)d_ws;

  unsigned short* rb   = (unsigned short*)(ws);            // 524288 B
  unsigned char*  kb8  = (unsigned char*) (ws + 524288);   // 65536 B
  int*            tokT = (int*)           (ws + 589824);   // 819200 B
  float*          hbuf = (float*)         (ws + 1409024);  // 1048576 B
  float*          obuf = (float*)         (ws + 2457600);  // 262144 B

  const int SMEM_BYTES = 153600;
  hipFuncSetAttribute((const void*)lstm_kernel,
                      hipFuncAttributeMaxDynamicSharedMemorySize, SMEM_BYTES);

  prep_kernel  <<<1024, 256, 0, stream>>>(inp, kern, rec, rb, kb8, tokT);
  lstm_kernel  <<<64, 512, SMEM_BYTES, stream>>>(emb, bias, rb, kb8, tokT, hbuf);
  dense_kernel <<<256, 256, 0, stream>>>(hbuf, dw, db, obuf);
  logits_kernel<<<dim3(391, 4), 256, 0, stream>>>(obuf, emb, dst);
  (void)in_sizes; (void)n_in; (void)out_size; (void)ws_size;
}

// Round 4
// 1670.288 us; speedup vs baseline: 1.1154x; 1.1154x over previous
//
#include <hip/hip_runtime.h>
#include <cstdint>
#include <cstddef>

#define SS 200
#define NV 100001   // V+1

using short8 = __attribute__((ext_vector_type(8))) short;
using f32x4  = __attribute__((ext_vector_type(4))) float;

__device__ __forceinline__ unsigned short f2bf(float f){
  unsigned int x = __float_as_uint(f);
  x += 0x7fffu + ((x >> 16) & 1u);
  return (unsigned short)(x >> 16);
}
__device__ __forceinline__ float bf2f(unsigned short b){
  return __uint_as_float(((unsigned int)b) << 16);
}
__device__ __forceinline__ float sigm(float x){
  return __builtin_amdgcn_rcpf(1.0f + exp2f(x * -1.44269504f));
}

#define MFB(a,b,c) __builtin_amdgcn_mfma_f32_16x16x32_bf16((a),(b),(c),0,0,0)
#define MF8(a,b,c) __builtin_amdgcn_mfma_f32_16x16x32_fp8_fp8((a),(b),(c),0,0,0)

// ---------------- prep: coalesced-read weight swizzle + token transpose -------------
// rb  : rec_kernel bf16 frags  [w(8)][t(8)][kt(8)][lane(64)][j(8)]
// kb8 : kernel fp8 frags       [w(8)][t(8)][kt(2)][lane(64)][j(8)]
// tokT: tokens transposed [s][b]
__global__ void prep_kernel(const int* __restrict__ inp,
                            const float* __restrict__ kern,
                            const float* __restrict__ rec,
                            unsigned short* __restrict__ rb,
                            unsigned char* __restrict__ kb8,
                            int* __restrict__ tokT){
  int idx = blockIdx.x * 256 + threadIdx.x;
  if (idx < 262144){                    // rec: 256 x 1024, coalesced read
    int k = idx >> 10, col = idx & 1023;
    int gg = col >> 8, w = (col >> 5) & 7, hh = (col >> 4) & 1, l15 = col & 15;
    int kt = k >> 5, hi = (k >> 3) & 3, j = k & 7;
    int lane = l15 + (hi << 4);
    int t = gg * 2 + hh;
    rb[(((w*8 + t)*8 + kt) << 9) + lane*8 + j] = f2bf(rec[idx]);
  }
  if (idx < 65536){                     // kernel: 64 x 1024
    int k = idx >> 10, col = idx & 1023;
    int gg = col >> 8, w = (col >> 5) & 7, hh = (col >> 4) & 1, l15 = col & 15;
    int kt = k >> 5, hi = (k >> 3) & 3, j = k & 7;
    int lane = l15 + (hi << 4);
    int t = gg * 2 + hh;
    int p = __builtin_amdgcn_cvt_pk_fp8_f32(kern[idx], 0.0f, 0, false);
    kb8[(((w*8 + t)*2 + kt) << 9) + lane*8 + j] = (unsigned char)(p & 0xff);
  }
  if (idx < 204800){                    // token transpose
    int s = idx >> 10, b = idx & 1023;
    tokT[idx] = inp[b * SS + s];
  }
}

// ---------------- LSTM: 64 blocks x 1024 thr (16 waves), 16 batch rows per block ----
// Wave wv = (w, hh): owns the 4 GATE tiles t = {hh, 2+hh, 4+hh, 6+hh} for u-cols
// w*32+hh*16..+15. Per-thread: i,f,g,o for 4 consecutive u (l4*4+r), batch l15.
// 16 waves = 4/SIMD => HARD 128-VGPR cap; per-wave demand ~120 (Wr 64 + S 16 + acc 16
// + c 4 + temps) => fits (rounds 1-3: ~240 live at the allocator's 128 cap = spill).
// LDS: h(8K, single-buffer, masked rows skip write) | xA(1K) | rBl kt4 (64K) |
//      kBl fp8 (64K) | biasL(4K) = 144384 B
__global__ void __attribute__((amdgpu_flat_work_group_size(1024, 1024),
                               amdgpu_waves_per_eu(4, 4)))
lstm_kernel(const float* __restrict__ emb,
            const float* __restrict__ bias,
            const unsigned short* __restrict__ rb,
            const unsigned char* __restrict__ kb8,
            const int* __restrict__ tokT,
            float* __restrict__ hout){
  extern __shared__ char smem[];
  char*  const h_lds = smem;                    // 8192
  char*  const xA    = smem + 8192;             // 1024
  char*  const rBl   = smem + 9216;             // 65536 (rec kt4)
  char*  const kBl   = smem + 74752;            // 65536 (kernel fp8)
  float* const biasL = (float*)(smem + 140288); // 4096
  const int tid  = threadIdx.x;
  const int lane = tid & 63;
  const int wv   = tid >> 6;       // 0..15
  const int w    = wv >> 1;        // 0..7
  const int hh   = wv & 1;
  const int l15  = lane & 15;
  const int l4   = lane >> 4;
  const int b0   = blockIdx.x << 4;

  // frag of rec: tile t = gg*2+hh of wave-pair w, K-tile kt
  #define RBF(gg,kt) (*(const short8*)(rb + (((w*8 + ((gg)*2+hh))*8 + (kt)) << 9) + (lane<<3)))

  // ---- stage rBl (rec kt4 frags, 64 x 1KB): thread = frag tid>>4, 64B part tid&15
  {
    int fid = tid >> 4, p = tid & 15;
    const int4* src = (const int4*)(rb + ((fid*8 + 4) << 9) + p*32);
    int4* dst = (int4*)(rBl + fid*1024 + p*64);
    #pragma unroll
    for (int q = 0; q < 4; ++q) dst[q] = src[q];
  }
  // ---- stage kBl (64KB linear copy): 64B per thread
  {
    const int4* src = (const int4*)(kb8 + tid*64);
    int4* dst = (int4*)(kBl + tid*64);
    #pragma unroll
    for (int q = 0; q < 4; ++q) dst[q] = src[q];
  }
  biasL[tid] = bias[tid];
  *(unsigned long long*)(h_lds + tid*8) = 0ull;   // h0 = 0

  // ---- stage x for s=0: wave wv handles batch row wv, elem = lane (coalesced row)
  {
    int tok0 = tokT[b0 + wv];
    float xv = emb[(size_t)tok0 * 64 + lane];
    int p = __builtin_amdgcn_cvt_pk_fp8_f32(xv, xv, 0, false);
    int kt = lane >> 5, lp = wv + ((((lane & 31) >> 3)) << 4), j = lane & 7;
    *(unsigned char*)(xA + kt*512 + lp*8 + j) = (unsigned char)(p & 0xff);
  }

  // resident rec frags kt0-3 for this wave's 4 gate-tiles (64 VGPRs)
  short8 Wr[4][4];
  #pragma unroll
  for (int kt = 0; kt < 4; ++kt)
    #pragma unroll
    for (int gg = 0; gg < 4; ++gg) Wr[kt][gg] = RBF(gg, kt);

  __syncthreads();

  // stream buffer: kt5 for step 0
  short8 S[4];
  #pragma unroll
  for (int gg = 0; gg < 4; ++gg) S[gg] = RBF(gg, 5);

  float c[4] = {0.f, 0.f, 0.f, 0.f};

  #pragma unroll 1
  for (int s = 0; s < SS; ++s){
    // early loads: mask token (per-thread) + next x row (wave-uniform token)
    int tk = tokT[s*1024 + b0 + l15];
    float xvn = 0.f;
    if (s + 1 < SS){
      int tok_n = tokT[(s+1)*1024 + b0 + wv];
      xvn = emb[(size_t)tok_n * 64 + lane];
    }

    // acc init from bias (broadcast ds_read_b128): acc[gg] = gate gg
    f32x4 acc[4];
    #pragma unroll
    for (int gg = 0; gg < 4; ++gg)
      acc[gg] = *(const f32x4*)(biasL + gg*256 + w*32 + hh*16 + (l4<<2));

    // kt5 (S from previous step / prologue)
    {
      short8 h5 = *(const short8*)(h_lds + 5*1024 + (lane<<4));
      #pragma unroll
      for (int gg = 0; gg < 4; ++gg) acc[gg] = MFB(S[gg], h5, acc[gg]);
    }
    #pragma unroll
    for (int gg = 0; gg < 4; ++gg) S[gg] = RBF(gg, 6);   // issue kt6

    // kt0-3 (VGPR-resident) — covers kt6 latency
    #pragma unroll
    for (int kt = 0; kt < 4; ++kt){
      short8 h = *(const short8*)(h_lds + kt*1024 + (lane<<4));
      #pragma unroll
      for (int gg = 0; gg < 4; ++gg) acc[gg] = MFB(Wr[kt][gg], h, acc[gg]);
    }

    // kt6
    {
      short8 h6 = *(const short8*)(h_lds + 6*1024 + (lane<<4));
      #pragma unroll
      for (int gg = 0; gg < 4; ++gg) acc[gg] = MFB(S[gg], h6, acc[gg]);
    }
    #pragma unroll
    for (int gg = 0; gg < 4; ++gg) S[gg] = RBF(gg, 7);   // issue kt7

    // kt4 (LDS weights) + x (fp8) — covers kt7 latency
    {
      short8 h4 = *(const short8*)(h_lds + 4*1024 + (lane<<4));
      #pragma unroll
      for (int gg = 0; gg < 4; ++gg){
        short8 bw = *(const short8*)(rBl + (w*8 + gg*2+hh)*1024 + (lane<<4));
        acc[gg] = MFB(bw, h4, acc[gg]);
      }
    }
    {
      long ax0 = *(const long*)(xA + (lane<<3));
      long ax1 = *(const long*)(xA + 512 + (lane<<3));
      #pragma unroll
      for (int gg = 0; gg < 4; ++gg){
        long bx0 = *(const long*)(kBl + (w*8 + gg*2+hh)*1024 + (lane<<3));
        long bx1 = *(const long*)(kBl + (w*8 + gg*2+hh)*1024 + 512 + (lane<<3));
        acc[gg] = MF8(bx0, ax0, acc[gg]);
        acc[gg] = MF8(bx1, ax1, acc[gg]);
      }
    }

    // kt7
    {
      short8 h7 = *(const short8*)(h_lds + 7*1024 + (lane<<4));
      #pragma unroll
      for (int gg = 0; gg < 4; ++gg) acc[gg] = MFB(S[gg], h7, acc[gg]);
    }
    #pragma unroll
    for (int gg = 0; gg < 4; ++gg) S[gg] = RBF(gg, 5);   // issue kt5 for NEXT step

    // gates: thread owns i,f,g,o for its 4 u; masked rows keep c and skip h write
    unsigned long long pk = 0ull;
    #pragma unroll
    for (int r = 0; r < 4; ++r){
      float si = sigm(acc[0][r]);
      float sf = sigm(acc[1][r]);
      float sg = sigm(acc[2][r]);
      float so = sigm(acc[3][r]);
      float cn = sf * c[r] + si * sg;
      float hv = so * sigm(cn);
      if (tk != 0) c[r] = cn;
      pk |= ((unsigned long long)f2bf(hv)) << (16*r);
    }

    __syncthreads();   // all reads of h_lds / xA done
    if (tk != 0){
      int lane_a = l15 + ((hh*2 + (l4 >> 1)) << 4);
      *(unsigned long long*)(h_lds + (w<<10) + lane_a*16 + ((l4 & 1) << 3)) = pk;
    }
    if (s + 1 < SS){
      int p = __builtin_amdgcn_cvt_pk_fp8_f32(xvn, xvn, 0, false);
      int kt = lane >> 5, lp = wv + ((((lane & 31) >> 3)) << 4), j = lane & 7;
      *(unsigned char*)(xA + kt*512 + lp*8 + j) = (unsigned char)(p & 0xff);
    }
    __syncthreads();   // h/x for next step visible
  }

  // final h: read back from LDS (bf16) — thread's slot holds u0..u0+3 for batch l15
  {
    int lane_a = l15 + ((hh*2 + (l4 >> 1)) << 4);
    unsigned long long pk =
      *(const unsigned long long*)(h_lds + (w<<10) + lane_a*16 + ((l4 & 1) << 3));
    int u0 = w*32 + hh*16 + (l4 << 2);
    *(float4*)(hout + (b0 + l15)*256 + u0) =
      make_float4(bf2f((unsigned short)(pk        & 0xffff)),
                  bf2f((unsigned short)((pk>>16)  & 0xffff)),
                  bf2f((unsigned short)((pk>>32)  & 0xffff)),
                  bf2f((unsigned short)((pk>>48)  & 0xffff)));
  }
  #undef RBF
}

// ---------------- dense: out = h @ dense_w + dense_b  (1024x64, K=256) --------------
__global__ void dense_kernel(const float* __restrict__ h,
                             const float* __restrict__ dw,
                             const float* __restrict__ db,
                             float* __restrict__ outv){
  int tid = threadIdx.x;
  int e = tid & 63;
  int b = blockIdx.x * 4 + (tid >> 6);
  const float* hb = h + b * 256;
  float a = db[e];
  #pragma unroll 8
  for (int u = 0; u < 256; ++u) a = fmaf(hb[u], dw[u*64 + e], a);
  outv[b*64 + e] = a;
}

// ---------------- logits: dst = out @ emb.T  (1024 x 100001, K=64, fp32) ------------
__global__ void __launch_bounds__(256)
logits_kernel(const float* __restrict__ outv,
              const float* __restrict__ emb,
              float* __restrict__ dst){
  int v = blockIdx.x * 256 + threadIdx.x;
  const bool valid = (v < NV);
  const int vs = valid ? v : 0;
  const int bb = blockIdx.y * 256;
  float er[64];
  #pragma unroll
  for (int q = 0; q < 16; ++q){
    float4 tq = *(const float4*)(emb + (size_t)vs * 64 + q*4);
    er[q*4+0] = tq.x; er[q*4+1] = tq.y; er[q*4+2] = tq.z; er[q*4+3] = tq.w;
  }
  for (int b = bb; b < bb + 256; ++b){
    const float* ob = outv + b*64;   // wave-uniform -> scalar loads
    float a0 = 0.f, a1 = 0.f;
    #pragma unroll
    for (int e = 0; e < 64; e += 2){
      a0 = fmaf(ob[e],   er[e],   a0);
      a1 = fmaf(ob[e+1], er[e+1], a1);
    }
    if (valid) dst[(size_t)b * NV + v] = a0 + a1;
  }
}

extern "C" void kernel_launch(void* const* d_in, const int* in_sizes, int n_in,
                              void* d_out, int out_size, void* d_ws, size_t ws_size,
                              hipStream_t stream){
  const int*   inp  = (const int*)  d_in[0];
  const float* emb  = (const float*)d_in[1];
  const float* kern = (const float*)d_in[2];
  const float* rec  = (const float*)d_in[3];
  const float* bias = (const float*)d_in[4];
  const float* dw   = (const float*)d_in[5];
  const float* db   = (const float*)d_in[6];
  float* dst = (float*)d_out;
  char* ws = (char*)d_ws;

  unsigned short* rb   = (unsigned short*)(ws);            // 524288 B
  unsigned char*  kb8  = (unsigned char*) (ws + 524288);   // 65536 B
  int*            tokT = (int*)           (ws + 589824);   // 819200 B
  float*          hbuf = (float*)         (ws + 1409024);  // 1048576 B
  float*          obuf = (float*)         (ws + 2457600);  // 262144 B

  const int SMEM_BYTES = 144384;
  hipFuncSetAttribute((const void*)lstm_kernel,
                      hipFuncAttributeMaxDynamicSharedMemorySize, SMEM_BYTES);

  prep_kernel  <<<1024, 256, 0, stream>>>(inp, kern, rec, rb, kb8, tokT);
  lstm_kernel  <<<64, 1024, SMEM_BYTES, stream>>>(emb, bias, rb, kb8, tokT, hbuf);
  dense_kernel <<<256, 256, 0, stream>>>(hbuf, dw, db, obuf);
  logits_kernel<<<dim3(391, 4), 256, 0, stream>>>(obuf, emb, dst);
  (void)in_sizes; (void)n_in; (void)out_size; (void)ws_size;
}

// Round 5
// 1503.858 us; speedup vs baseline: 1.2388x; 1.1107x over previous
//
#include <hip/hip_runtime.h>
#include <cstdint>
#include <cstddef>

#define SS 200
#define NV 100001              // V+1
#define XP_CHUNK 6553600ull    // bytes of xp per lstm-block: 200*1024*32

using short8 = __attribute__((ext_vector_type(8))) short;
using f32x4  = __attribute__((ext_vector_type(4))) float;

__device__ __forceinline__ unsigned short f2bf(float f){
  unsigned int x = __float_as_uint(f);
  x += 0x7fffu + ((x >> 16) & 1u);
  return (unsigned short)(x >> 16);
}
__device__ __forceinline__ float bf2f(unsigned short b){
  return __uint_as_float(((unsigned int)b) << 16);
}
__device__ __forceinline__ float sigm(float x){
  return __builtin_amdgcn_rcpf(1.0f + exp2f(x * -1.44269504f));
}

#define MFB(a,b,c) __builtin_amdgcn_mfma_f32_16x16x32_bf16((a),(b),(c),0,0,0)

// ---------------- prep: weight swizzle (coalesced reads) + token transpose ----------
// rb  : rec_kernel bf16 frags [w(8)][t(8)][kt(8)][lane(64)][j(8)]   (A-operand frags)
// kbf : kernel bf16 frags     [zt(64)][kt(2)][lane(64)][j(8)]       (A-operand frags)
// tokT: tokens transposed [s][b]
__global__ void prep_kernel(const int* __restrict__ inp,
                            const float* __restrict__ kern,
                            const float* __restrict__ rec,
                            unsigned short* __restrict__ rb,
                            unsigned short* __restrict__ kbf,
                            int* __restrict__ tokT){
  int idx = blockIdx.x * 256 + threadIdx.x;
  if (idx < 262144){                    // rec: 256 x 1024
    int k = idx >> 10, col = idx & 1023;
    int gg = col >> 8, w = (col >> 5) & 7, hh = (col >> 4) & 1, l15 = col & 15;
    int kt = k >> 5, hi = (k >> 3) & 3, j = k & 7;
    int lane = l15 + (hi << 4);
    int t = gg * 2 + hh;
    rb[(((w*8 + t)*8 + kt) << 9) + lane*8 + j] = f2bf(rec[idx]);
  }
  if (idx < 65536){                     // kernel: 64 x 1024
    int k = idx >> 10, col = idx & 1023;
    int zt = col >> 4, l15 = col & 15;
    int kt = k >> 5, hi = (k >> 3) & 3, j = k & 7;
    kbf[(((zt << 1) + kt) << 9) + (l15 + (hi << 4))*8 + j] = f2bf(kern[idx]);
  }
  if (idx < 204800){                    // token transpose
    int s = idx >> 10, b = idx & 1023;
    tokT[idx] = inp[b * SS + s];
  }
}

// ---------------- xproj: z_x[b][s][:] = emb[tok] @ kernel + bias --------------------
// Output written bf16 in the LSTM's per-thread fragment order:
//   chunk(blk) + s*32768 + tid_l*32 + slot*2 , slot = gg*4 + r  (16 bf16 per thread)
// 12800 blocks (= 64 lstm-blocks x 200 steps), 256 thr (4 waves), MFMA 16x16x32.
__global__ void __launch_bounds__(256)
xproj_kernel(const float* __restrict__ emb,
             const float* __restrict__ bias,
             const unsigned short* __restrict__ kbf,
             const int* __restrict__ tokT,
             float* __restrict__ dout,
             char* __restrict__ wsxp){
  __shared__ char ldsB[2048];
  const int bid = blockIdx.x;
  const int blk = bid / 200;
  const int s   = bid - blk * 200;
  const int b0  = blk << 4;
  const int tid = threadIdx.x;
  const int lane = tid & 63;
  const int w4  = tid >> 6;
  const int l15 = lane & 15;
  const int l4  = lane >> 4;

  // stage x rows (16 rows x 64 elems) into B-fragment order (bf16)
  {
    int row = tid >> 4, e0 = (tid & 15) << 2;
    int tok = tokT[s*1024 + b0 + row];
    float4 xv = *(const float4*)(emb + (size_t)tok * 64 + e0);
    float vq[4] = {xv.x, xv.y, xv.z, xv.w};
    #pragma unroll
    for (int q = 0; q < 4; ++q){
      int e = e0 + q, kt = e >> 5, hi = (e & 31) >> 3, j = e & 7;
      *(unsigned short*)(ldsB + kt*1024 + (row + (hi << 4))*16 + (j << 1)) = f2bf(vq[q]);
    }
  }
  __syncthreads();
  short8 xb0 = *(const short8*)(ldsB + (lane << 4));
  short8 xb1 = *(const short8*)(ldsB + 1024 + (lane << 4));

  char* xpb = (blk < 62) ? ((char*)dout + (size_t)blk * XP_CHUNK)
                         : (wsxp + (size_t)(blk - 62) * XP_CHUNK);
  xpb += (size_t)s * 32768;

  #pragma unroll 4
  for (int i = 0; i < 16; ++i){
    int zt = (w4 << 4) + i;
    f32x4 acc = *(const f32x4*)(bias + (zt << 4) + (l4 << 2));
    short8 a0 = *(const short8*)(kbf + (((zt << 1) + 0) << 9) + (lane << 3));
    short8 a1 = *(const short8*)(kbf + (((zt << 1) + 1) << 9) + (lane << 3));
    acc = MFB(a0, xb0, acc);
    acc = MFB(a1, xb1, acc);
    unsigned int p0, p1;
    asm("v_cvt_pk_bf16_f32 %0, %1, %2" : "=v"(p0) : "v"(acc[0]), "v"(acc[1]));
    asm("v_cvt_pk_bf16_f32 %0, %1, %2" : "=v"(p1) : "v"(acc[2]), "v"(acc[3]));
    int gg = zt >> 4, w = (zt >> 1) & 7, hh = zt & 1;
    int tid_l = ((w << 1) + hh)*64 + (l4 << 4) + l15;
    *(uint2*)(xpb + tid_l*32 + (gg << 3)) = make_uint2(p0, p1);
  }
}

// ---------------- LSTM: 64 blocks x 1024 thr (16 waves), 16 batch rows per block ----
// Wave (w,hh) owns 4 gate-tiles (u-cols w*32+hh*16..+15). Thread: batch l15, u l4*4+r.
// Weights: kt0-2 VGPR (48), kt4/kt5 LDS (128 KB), kt3/6/7 streamed from L2 (one
// 16-reg buffer, issue-early). x-path fully precomputed (xp stream, 2 dwordx4/step).
// One barrier/step: double-buffered h, always-write (masked rows rewrite pkPrev).
// Arch VGPR demand ~114 <= 128 cap at 4 waves/SIMD.
// LDS: h 2x8K | rBl kt4 64K | rBl2 kt5 64K = 147456 B
__global__ void __attribute__((amdgpu_flat_work_group_size(1024, 1024),
                               amdgpu_waves_per_eu(4, 4)))
lstm_kernel(const unsigned short* __restrict__ rb,
            const int* __restrict__ tokT,
            const float* __restrict__ dout_xp,
            const char* __restrict__ wsxp,
            float* __restrict__ hout){
  extern __shared__ char smem[];
  char* const hA   = smem;              // 8192
  char* const hB   = smem + 8192;       // 8192
  char* const rBl  = smem + 16384;      // 65536 (rec kt4)
  char* const rBl2 = smem + 81920;      // 65536 (rec kt5)
  const int tid  = threadIdx.x;
  const int lane = tid & 63;
  const int wv   = tid >> 6;
  const int w    = wv >> 1;
  const int hh   = wv & 1;
  const int l15  = lane & 15;
  const int l4   = lane >> 4;
  const int blk  = blockIdx.x;
  const int b0   = blk << 4;

  #define RBF(gg,kt) (*(const short8*)(rb + (((w*8 + ((gg)*2+hh))*8 + (kt)) << 9) + (lane<<3)))

  // stage rBl (kt4) and rBl2 (kt5): thread = frag tid>>4, 64B part tid&15
  {
    int fid = tid >> 4, p = tid & 15;
    const int4* s4 = (const int4*)(rb + ((fid*8 + 4) << 9) + p*32);
    const int4* s5 = (const int4*)(rb + ((fid*8 + 5) << 9) + p*32);
    int4* d4 = (int4*)(rBl  + fid*1024 + p*64);
    int4* d5 = (int4*)(rBl2 + fid*1024 + p*64);
    #pragma unroll
    for (int q = 0; q < 4; ++q){ d4[q] = s4[q]; d5[q] = s5[q]; }
  }
  *(unsigned long long*)(hA + tid*8) = 0ull;   // h0 = 0

  // resident rec frags kt0-2 (48 VGPRs)
  short8 Wr[3][4];
  #pragma unroll
  for (int kt = 0; kt < 3; ++kt)
    #pragma unroll
    for (int gg = 0; gg < 4; ++gg) Wr[kt][gg] = RBF(gg, kt);

  const char* xp_ptr = ((blk < 62) ? ((const char*)dout_xp + (size_t)blk * XP_CHUNK)
                                   : (wsxp + (size_t)(blk - 62) * XP_CHUNK)) + tid*32;
  const int* tok_ptr = tokT + b0 + l15;

  float c[4] = {0.f, 0.f, 0.f, 0.f};
  unsigned long long pkPrev = 0ull;
  const int lane_a  = l15 + ((hh*2 + (l4 >> 1)) << 4);
  const int wb_off  = (w << 10) + lane_a*16 + ((l4 & 1) << 3);

  __syncthreads();

  #pragma unroll 1
  for (int s = 0; s < SS; ++s){
    const char* rd = (s & 1) ? hB : hA;
    char*       wr2 = (s & 1) ? hA : hB;

    // issue streams early: kt3 weights + xp (this step) + mask token
    short8 S[4];
    #pragma unroll
    for (int gg = 0; gg < 4; ++gg) S[gg] = RBF(gg, 3);
    uint4 xa = *(const uint4*)(xp_ptr);
    uint4 xc = *(const uint4*)(xp_ptr + 16);
    int tk = *tok_ptr;
    xp_ptr += 32768; tok_ptr += 1024;

    f32x4 acc[4];
    #pragma unroll
    for (int gg = 0; gg < 4; ++gg) acc[gg] = f32x4{0.f, 0.f, 0.f, 0.f};

    // kt0-2 (VGPR weights)
    #pragma unroll
    for (int kt = 0; kt < 3; ++kt){
      short8 h = *(const short8*)(rd + kt*1024 + (lane << 4));
      #pragma unroll
      for (int gg = 0; gg < 4; ++gg) acc[gg] = MFB(Wr[kt][gg], h, acc[gg]);
    }
    // kt3 (streamed; covered by 12 MFMAs above)
    {
      short8 h3 = *(const short8*)(rd + 3*1024 + (lane << 4));
      #pragma unroll
      for (int gg = 0; gg < 4; ++gg) acc[gg] = MFB(S[gg], h3, acc[gg]);
    }
    #pragma unroll
    for (int gg = 0; gg < 4; ++gg) S[gg] = RBF(gg, 6);   // issue kt6
    // kt4 (LDS weights)
    {
      short8 h4 = *(const short8*)(rd + 4*1024 + (lane << 4));
      #pragma unroll
      for (int gg = 0; gg < 4; ++gg){
        short8 bw = *(const short8*)(rBl + (w*8 + gg*2+hh)*1024 + (lane << 4));
        acc[gg] = MFB(bw, h4, acc[gg]);
      }
    }
    // kt6 (streamed)
    {
      short8 h6 = *(const short8*)(rd + 6*1024 + (lane << 4));
      #pragma unroll
      for (int gg = 0; gg < 4; ++gg) acc[gg] = MFB(S[gg], h6, acc[gg]);
    }
    #pragma unroll
    for (int gg = 0; gg < 4; ++gg) S[gg] = RBF(gg, 7);   // issue kt7
    // kt5 (LDS weights)
    {
      short8 h5 = *(const short8*)(rd + 5*1024 + (lane << 4));
      #pragma unroll
      for (int gg = 0; gg < 4; ++gg){
        short8 bw = *(const short8*)(rBl2 + (w*8 + gg*2+hh)*1024 + (lane << 4));
        acc[gg] = MFB(bw, h5, acc[gg]);
      }
    }
    // kt7 (streamed)
    {
      short8 h7 = *(const short8*)(rd + 7*1024 + (lane << 4));
      #pragma unroll
      for (int gg = 0; gg < 4; ++gg) acc[gg] = MFB(S[gg], h7, acc[gg]);
    }

    // add precomputed x-projection (+bias): slot = gg*4+r, bf16 -> f32
    {
      const unsigned int uu[8] = {xa.x, xa.y, xa.z, xa.w, xc.x, xc.y, xc.z, xc.w};
      #pragma unroll
      for (int gg = 0; gg < 4; ++gg)
        #pragma unroll
        for (int r = 0; r < 4; ++r){
          int slot = gg*4 + r;
          unsigned int u = uu[slot >> 1];
          unsigned int bits = (slot & 1) ? (u & 0xffff0000u) : (u << 16);
          acc[gg][r] += __uint_as_float(bits);
        }
    }

    // gates (all-sigmoid LSTM); masked rows keep c and h
    float hv0, hv1, hv2, hv3;
    #pragma unroll
    for (int r = 0; r < 4; ++r){
      float si = sigm(acc[0][r]);
      float sf = sigm(acc[1][r]);
      float sg = sigm(acc[2][r]);
      float so = sigm(acc[3][r]);
      float cn = sf * c[r] + si * sg;
      float hv = so * sigm(cn);
      if (tk != 0) c[r] = cn;
      if (r == 0) hv0 = hv; else if (r == 1) hv1 = hv;
      else if (r == 2) hv2 = hv; else hv3 = hv;
    }
    unsigned int pLo, pHi;
    asm("v_cvt_pk_bf16_f32 %0, %1, %2" : "=v"(pLo) : "v"(hv0), "v"(hv1));
    asm("v_cvt_pk_bf16_f32 %0, %1, %2" : "=v"(pHi) : "v"(hv2), "v"(hv3));
    unsigned long long pkNew = (((unsigned long long)pHi) << 32) | pLo;
    unsigned long long pk = (tk != 0) ? pkNew : pkPrev;
    pkPrev = pk;
    *(unsigned long long*)(wr2 + wb_off) = pk;   // always write (double buffer)

    __syncthreads();   // single barrier per step
  }

  // final h (fp32) from pkPrev
  {
    int u0 = w*32 + hh*16 + (l4 << 2);
    *(float4*)(hout + (b0 + l15)*256 + u0) =
      make_float4(bf2f((unsigned short)( pkPrev        & 0xffff)),
                  bf2f((unsigned short)((pkPrev >> 16) & 0xffff)),
                  bf2f((unsigned short)((pkPrev >> 32) & 0xffff)),
                  bf2f((unsigned short)((pkPrev >> 48) & 0xffff)));
  }
  #undef RBF
}

// ---------------- dense: out = h @ dense_w + dense_b  (1024x64, K=256) --------------
__global__ void dense_kernel(const float* __restrict__ h,
                             const float* __restrict__ dw,
                             const float* __restrict__ db,
                             float* __restrict__ outv){
  int tid = threadIdx.x;
  int e = tid & 63;
  int b = blockIdx.x * 4 + (tid >> 6);
  const float* hb = h + b * 256;
  float a = db[e];
  #pragma unroll 8
  for (int u = 0; u < 256; ++u) a = fmaf(hb[u], dw[u*64 + e], a);
  outv[b*64 + e] = a;
}

// ---------------- logits: dst = out @ emb.T  (1024 x 100001, K=64, fp32) ------------
__global__ void __launch_bounds__(256)
logits_kernel(const float* __restrict__ outv,
              const float* __restrict__ emb,
              float* __restrict__ dst){
  int v = blockIdx.x * 256 + threadIdx.x;
  const bool valid = (v < NV);
  const int vs = valid ? v : 0;
  const int bb = blockIdx.y * 256;
  float er[64];
  #pragma unroll
  for (int q = 0; q < 16; ++q){
    float4 tq = *(const float4*)(emb + (size_t)vs * 64 + q*4);
    er[q*4+0] = tq.x; er[q*4+1] = tq.y; er[q*4+2] = tq.z; er[q*4+3] = tq.w;
  }
  for (int b = bb; b < bb + 256; ++b){
    const float* ob = outv + b*64;   // wave-uniform -> scalar loads
    float a0 = 0.f, a1 = 0.f;
    #pragma unroll
    for (int e = 0; e < 64; e += 2){
      a0 = fmaf(ob[e],   er[e],   a0);
      a1 = fmaf(ob[e+1], er[e+1], a1);
    }
    if (valid) dst[(size_t)b * NV + v] = a0 + a1;
  }
}

extern "C" void kernel_launch(void* const* d_in, const int* in_sizes, int n_in,
                              void* d_out, int out_size, void* d_ws, size_t ws_size,
                              hipStream_t stream){
  const int*   inp  = (const int*)  d_in[0];
  const float* emb  = (const float*)d_in[1];
  const float* kern = (const float*)d_in[2];
  const float* rec  = (const float*)d_in[3];
  const float* bias = (const float*)d_in[4];
  const float* dw   = (const float*)d_in[5];
  const float* db   = (const float*)d_in[6];
  float* dst = (float*)d_out;
  char* ws = (char*)d_ws;

  unsigned short* rb   = (unsigned short*)(ws);            // 524288 B
  unsigned short* kbf  = (unsigned short*)(ws + 524288);   // 131072 B
  int*            tokT = (int*)           (ws + 655360);   // 819200 B
  float*          hbuf = (float*)         (ws + 1474560);  // 1048576 B
  float*          obuf = (float*)         (ws + 2523136);  // 262144 B
  char*           wsxp = (char*)          (ws + 2785280);  // 13107200 B (xp blks 62,63)

  const int SMEM_BYTES = 147456;
  hipFuncSetAttribute((const void*)lstm_kernel,
                      hipFuncAttributeMaxDynamicSharedMemorySize, SMEM_BYTES);

  prep_kernel  <<<1024, 256, 0, stream>>>(inp, kern, rec, rb, kbf, tokT);
  xproj_kernel <<<12800, 256, 0, stream>>>(emb, bias, kbf, tokT, dst, wsxp);
  lstm_kernel  <<<64, 1024, SMEM_BYTES, stream>>>(rb, tokT, dst, wsxp, hbuf);
  dense_kernel <<<256, 256, 0, stream>>>(hbuf, dw, db, obuf);
  logits_kernel<<<dim3(391, 4), 256, 0, stream>>>(obuf, emb, dst);
  (void)in_sizes; (void)n_in; (void)out_size; (void)ws_size;
}

// Round 6
// 1362.507 us; speedup vs baseline: 1.3674x; 1.1037x over previous
//
#include <hip/hip_runtime.h>
#include <cstdint>
#include <cstddef>

#define SS 200
#define NV 100001              // V+1
#define XP_CHUNK 6553600ull    // bytes of xp per lstm-block: 200*1024*32

using short8 = __attribute__((ext_vector_type(8))) short;
using f32x4  = __attribute__((ext_vector_type(4))) float;

__device__ __forceinline__ unsigned short f2bf(float f){
  unsigned int x = __float_as_uint(f);
  x += 0x7fffu + ((x >> 16) & 1u);
  return (unsigned short)(x >> 16);
}
__device__ __forceinline__ float bf2f(unsigned short b){
  return __uint_as_float(((unsigned int)b) << 16);
}
__device__ __forceinline__ float sigm(float x){
  return __builtin_amdgcn_rcpf(1.0f + exp2f(x * -1.44269504f));
}

#define MFB(a,b,c) __builtin_amdgcn_mfma_f32_16x16x32_bf16((a),(b),(c),0,0,0)

// ---------------- prep: weight swizzle + token transpose + mask bit-pack ------------
// rb   : rec_kernel bf16 frags [w(8)][t(8)][kt(8)][lane(64)][j(8)]  (A-operand frags)
// kbf  : kernel bf16 frags     [zt(64)][kt(2)][lane(64)][j(8)]      (A-operand frags)
// tokT : tokens transposed [s][b]                  (for xproj only)
// maskP: per-batch-row mask bits, 4 x u64 per row  (for lstm)
__global__ void prep_kernel(const int* __restrict__ inp,
                            const float* __restrict__ kern,
                            const float* __restrict__ rec,
                            unsigned short* __restrict__ rb,
                            unsigned short* __restrict__ kbf,
                            int* __restrict__ tokT,
                            unsigned long long* __restrict__ maskP){
  int idx = blockIdx.x * 256 + threadIdx.x;
  if (idx < 262144){                    // rec: 256 x 1024, coalesced read
    int k = idx >> 10, col = idx & 1023;
    int gg = col >> 8, w = (col >> 5) & 7, hh = (col >> 4) & 1, l15 = col & 15;
    int kt = k >> 5, hi = (k >> 3) & 3, j = k & 7;
    int lane = l15 + (hi << 4);
    int t = gg * 2 + hh;
    rb[(((w*8 + t)*8 + kt) << 9) + lane*8 + j] = f2bf(rec[idx]);
  }
  if (idx < 65536){                     // kernel: 64 x 1024
    int k = idx >> 10, col = idx & 1023;
    int zt = col >> 4, l15 = col & 15;
    int kt = k >> 5, hi = (k >> 3) & 3, j = k & 7;
    kbf[(((zt << 1) + kt) << 9) + (l15 + (hi << 4))*8 + j] = f2bf(kern[idx]);
  }
  if (idx < 204800){                    // token transpose
    int s = idx >> 10, b = idx & 1023;
    tokT[idx] = inp[b * SS + s];
  }
  if (idx < 4096){                      // mask bit-pack: b = idx>>2, seg = idx&3
    int b = idx >> 2, seg = idx & 3;
    unsigned long long bits = 0ull;
    int base = b * SS + seg * 64;
    int n = (seg < 3) ? 64 : (SS - 192);
    for (int i = 0; i < n; ++i)
      if (inp[base + i] != 0) bits |= (1ull << i);
    maskP[idx] = bits;
  }
}

// ---------------- xproj: z_x[b][s][:] = emb[tok] @ kernel + bias --------------------
// Output bf16 in the LSTM's per-thread fragment order:
//   chunk(blk) + s*32768 + tid*32 + gg*8  (uint2 = 4 bf16: r0..r3 of gate gg)
__global__ void __launch_bounds__(256)
xproj_kernel(const float* __restrict__ emb,
             const float* __restrict__ bias,
             const unsigned short* __restrict__ kbf,
             const int* __restrict__ tokT,
             float* __restrict__ dout,
             char* __restrict__ wsxp){
  __shared__ char ldsB[2048];
  const int bid = blockIdx.x;
  const int blk = bid / 200;
  const int s   = bid - blk * 200;
  const int b0  = blk << 4;
  const int tid = threadIdx.x;
  const int lane = tid & 63;
  const int w4  = tid >> 6;
  const int l15 = lane & 15;
  const int l4  = lane >> 4;

  // stage x rows (16 rows x 64 elems) into B-fragment order (bf16)
  {
    int row = tid >> 4, e0 = (tid & 15) << 2;
    int tok = tokT[s*1024 + b0 + row];
    float4 xv = *(const float4*)(emb + (size_t)tok * 64 + e0);
    float vq[4] = {xv.x, xv.y, xv.z, xv.w};
    #pragma unroll
    for (int q = 0; q < 4; ++q){
      int e = e0 + q, kt = e >> 5, hi = (e & 31) >> 3, j = e & 7;
      *(unsigned short*)(ldsB + kt*1024 + (row + (hi << 4))*16 + (j << 1)) = f2bf(vq[q]);
    }
  }
  __syncthreads();
  short8 xb0 = *(const short8*)(ldsB + (lane << 4));
  short8 xb1 = *(const short8*)(ldsB + 1024 + (lane << 4));

  char* xpb = (blk < 62) ? ((char*)dout + (size_t)blk * XP_CHUNK)
                         : (wsxp + (size_t)(blk - 62) * XP_CHUNK);
  xpb += (size_t)s * 32768;

  #pragma unroll 4
  for (int i = 0; i < 16; ++i){
    int zt = (w4 << 4) + i;
    f32x4 acc = *(const f32x4*)(bias + (zt << 4) + (l4 << 2));
    short8 a0 = *(const short8*)(kbf + (((zt << 1) + 0) << 9) + (lane << 3));
    short8 a1 = *(const short8*)(kbf + (((zt << 1) + 1) << 9) + (lane << 3));
    acc = MFB(a0, xb0, acc);
    acc = MFB(a1, xb1, acc);
    unsigned int p0, p1;
    asm("v_cvt_pk_bf16_f32 %0, %1, %2" : "=v"(p0) : "v"(acc[0]), "v"(acc[1]));
    asm("v_cvt_pk_bf16_f32 %0, %1, %2" : "=v"(p1) : "v"(acc[2]), "v"(acc[3]));
    int gg = zt >> 4, w = (zt >> 1) & 7, hh = zt & 1;
    int tid_l = ((w << 1) + hh)*64 + (l4 << 4) + l15;
    *(uint2*)(xpb + tid_l*32 + (gg << 3)) = make_uint2(p0, p1);
  }
}

// ---------------- LSTM: 64 blocks x 1024 thr (16 waves), 16 batch rows per block ----
// Wave (w,hh) owns 4 gate-tiles (u-cols w*32+hh*16..+15). Thread: batch l15, u l4*4+r.
// Latency-focused: xp(s+1) prefetched ACROSS the barrier; mask = register bitmask
// (no per-step token load); acc seeded from xp (short tail). Weights: kt0-2 VGPR,
// kt4/kt5 LDS, kt3/6/7 streamed from L2 via one rotating 16-reg buffer.
// LDS: h 2x8K | rBl kt4 64K | rBl2 kt5 64K = 147456 B
__global__ void __attribute__((amdgpu_flat_work_group_size(1024, 1024),
                               amdgpu_waves_per_eu(4, 4)))
lstm_kernel(const unsigned short* __restrict__ rb,
            const unsigned long long* __restrict__ maskP,
            const float* __restrict__ dout_xp,
            const char* __restrict__ wsxp,
            float* __restrict__ hout){
  extern __shared__ char smem[];
  char* const hA   = smem;              // 8192
  char* const hB   = smem + 8192;       // 8192
  char* const rBl  = smem + 16384;      // 65536 (rec kt4)
  char* const rBl2 = smem + 81920;      // 65536 (rec kt5)
  const int tid  = threadIdx.x;
  const int lane = tid & 63;
  const int wv   = tid >> 6;
  const int w    = wv >> 1;
  const int hh   = wv & 1;
  const int l15  = lane & 15;
  const int l4   = lane >> 4;
  const int blk  = blockIdx.x;
  const int b0   = blk << 4;

  #define RBF(gg,kt) (*(const short8*)(rb + (((w*8 + ((gg)*2+hh))*8 + (kt)) << 9) + (lane<<3)))

  // stage rBl (kt4) and rBl2 (kt5): thread = frag tid>>4, 64B part tid&15
  {
    int fid = tid >> 4, p = tid & 15;
    const int4* s4 = (const int4*)(rb + ((fid*8 + 4) << 9) + p*32);
    const int4* s5 = (const int4*)(rb + ((fid*8 + 5) << 9) + p*32);
    int4* d4 = (int4*)(rBl  + fid*1024 + p*64);
    int4* d5 = (int4*)(rBl2 + fid*1024 + p*64);
    #pragma unroll
    for (int q = 0; q < 4; ++q){ d4[q] = s4[q]; d5[q] = s5[q]; }
  }
  *(unsigned long long*)(hA + tid*8) = 0ull;   // h0 = 0

  // resident rec frags kt0-2 (48 VGPRs)
  short8 Wr[3][4];
  #pragma unroll
  for (int kt = 0; kt < 3; ++kt)
    #pragma unroll
    for (int gg = 0; gg < 4; ++gg) Wr[kt][gg] = RBF(gg, kt);

  const char* xp_base = ((blk < 62) ? ((const char*)dout_xp + (size_t)blk * XP_CHUNK)
                                    : (wsxp + (size_t)(blk - 62) * XP_CHUNK)) + tid*32;
  const unsigned long long* maskB = maskP + (size_t)(b0 + l15) * 4;

  // prologue: xp(0) + kt3(0)
  uint4 xca = *(const uint4*)(xp_base);
  uint4 xcb = *(const uint4*)(xp_base + 16);
  const char* xp_ptr = xp_base + 32768;   // -> step 1
  short8 S[4];
  #pragma unroll
  for (int gg = 0; gg < 4; ++gg) S[gg] = RBF(gg, 3);

  float c[4] = {0.f, 0.f, 0.f, 0.f};
  unsigned long long pkPrev = 0ull;
  const int lane_a = l15 + ((hh*2 + (l4 >> 1)) << 4);
  const int wb_off = (w << 10) + lane_a*16 + ((l4 & 1) << 3);

  __syncthreads();

  int s = 0;
  #pragma unroll 1
  for (int seg = 0; seg < 4; ++seg){
    unsigned long long cur = maskB[seg];
    const int nn = (seg < 3) ? 64 : (SS - 192);
    #pragma unroll 1
    for (int i = 0; i < nn; ++i, ++s){
      const char* rd  = (s & 1) ? hB : hA;
      char*       wr2 = (s & 1) ? hA : hB;

      // 1. issue xp(s+1) — crosses the end-of-step barrier in flight
      uint4 xna = *(const uint4*)(xp_ptr);
      uint4 xnb = *(const uint4*)(xp_ptr + 16);
      if (s < SS - 2) xp_ptr += 32768;

      // 2. acc seeded from xp(s) (bias + x-projection already folded in)
      f32x4 acc[4];
      #pragma unroll
      for (int gg = 0; gg < 4; ++gg){
        unsigned int u0 = (gg==0) ? xca.x : (gg==1) ? xca.z : (gg==2) ? xcb.x : xcb.z;
        unsigned int u1 = (gg==0) ? xca.y : (gg==1) ? xca.w : (gg==2) ? xcb.y : xcb.w;
        acc[gg] = f32x4{ __uint_as_float(u0 << 16),
                         __uint_as_float(u0 & 0xffff0000u),
                         __uint_as_float(u1 << 16),
                         __uint_as_float(u1 & 0xffff0000u) };
      }

      // 3. kt0-2 (VGPR weights) + kt3 (streamed, loaded last step)
      #pragma unroll
      for (int kt = 0; kt < 3; ++kt){
        short8 h = *(const short8*)(rd + kt*1024 + (lane << 4));
        #pragma unroll
        for (int gg = 0; gg < 4; ++gg) acc[gg] = MFB(Wr[kt][gg], h, acc[gg]);
      }
      {
        short8 h3 = *(const short8*)(rd + 3*1024 + (lane << 4));
        #pragma unroll
        for (int gg = 0; gg < 4; ++gg) acc[gg] = MFB(S[gg], h3, acc[gg]);
      }
      #pragma unroll
      for (int gg = 0; gg < 4; ++gg) S[gg] = RBF(gg, 6);   // issue kt6

      // 4. kt4 (LDS weights) — covers kt6 latency
      {
        short8 h4 = *(const short8*)(rd + 4*1024 + (lane << 4));
        #pragma unroll
        for (int gg = 0; gg < 4; ++gg){
          short8 bw = *(const short8*)(rBl + (w*8 + gg*2+hh)*1024 + (lane << 4));
          acc[gg] = MFB(bw, h4, acc[gg]);
        }
      }
      // 5. kt6 (streamed)
      {
        short8 h6 = *(const short8*)(rd + 6*1024 + (lane << 4));
        #pragma unroll
        for (int gg = 0; gg < 4; ++gg) acc[gg] = MFB(S[gg], h6, acc[gg]);
      }
      #pragma unroll
      for (int gg = 0; gg < 4; ++gg) S[gg] = RBF(gg, 7);   // issue kt7

      // 6. kt5 (LDS weights) — covers kt7 latency
      {
        short8 h5 = *(const short8*)(rd + 5*1024 + (lane << 4));
        #pragma unroll
        for (int gg = 0; gg < 4; ++gg){
          short8 bw = *(const short8*)(rBl2 + (w*8 + gg*2+hh)*1024 + (lane << 4));
          acc[gg] = MFB(bw, h5, acc[gg]);
        }
      }
      // 7. kt7 (streamed)
      {
        short8 h7 = *(const short8*)(rd + 7*1024 + (lane << 4));
        #pragma unroll
        for (int gg = 0; gg < 4; ++gg) acc[gg] = MFB(S[gg], h7, acc[gg]);
      }
      #pragma unroll
      for (int gg = 0; gg < 4; ++gg) S[gg] = RBF(gg, 3);   // issue kt3 for NEXT step

      // 8. gates (all-sigmoid LSTM); masked rows keep c and h
      int tkb = (int)(cur & 1ull);
      cur >>= 1;
      float hv0, hv1, hv2, hv3;
      #pragma unroll
      for (int r = 0; r < 4; ++r){
        float si = sigm(acc[0][r]);
        float sf = sigm(acc[1][r]);
        float sg = sigm(acc[2][r]);
        float so = sigm(acc[3][r]);
        float cn = sf * c[r] + si * sg;
        float hv = so * sigm(cn);
        if (tkb) c[r] = cn;
        if (r == 0) hv0 = hv; else if (r == 1) hv1 = hv;
        else if (r == 2) hv2 = hv; else hv3 = hv;
      }
      unsigned int pLo, pHi;
      asm("v_cvt_pk_bf16_f32 %0, %1, %2" : "=v"(pLo) : "v"(hv0), "v"(hv1));
      asm("v_cvt_pk_bf16_f32 %0, %1, %2" : "=v"(pHi) : "v"(hv2), "v"(hv3));
      unsigned long long pkNew = (((unsigned long long)pHi) << 32) | pLo;
      unsigned long long pk = tkb ? pkNew : pkPrev;
      pkPrev = pk;
      *(unsigned long long*)(wr2 + wb_off) = pk;   // always write (double buffer)

      // 9. rotate xp
      xca = xna; xcb = xnb;

      __syncthreads();   // single barrier per step
    }
  }

  // final h (fp32) from pkPrev
  {
    int u0 = w*32 + hh*16 + (l4 << 2);
    *(float4*)(hout + (b0 + l15)*256 + u0) =
      make_float4(bf2f((unsigned short)( pkPrev        & 0xffff)),
                  bf2f((unsigned short)((pkPrev >> 16) & 0xffff)),
                  bf2f((unsigned short)((pkPrev >> 32) & 0xffff)),
                  bf2f((unsigned short)((pkPrev >> 48) & 0xffff)));
  }
  #undef RBF
}

// ---------------- dense: out = h @ dense_w + dense_b  (1024x64, K=256) --------------
__global__ void dense_kernel(const float* __restrict__ h,
                             const float* __restrict__ dw,
                             const float* __restrict__ db,
                             float* __restrict__ outv){
  int tid = threadIdx.x;
  int e = tid & 63;
  int b = blockIdx.x * 4 + (tid >> 6);
  const float* hb = h + b * 256;
  float a = db[e];
  #pragma unroll 8
  for (int u = 0; u < 256; ++u) a = fmaf(hb[u], dw[u*64 + e], a);
  outv[b*64 + e] = a;
}

// ---------------- logits: dst = out @ emb.T  (1024 x 100001, K=64, fp32) ------------
__global__ void __launch_bounds__(256)
logits_kernel(const float* __restrict__ outv,
              const float* __restrict__ emb,
              float* __restrict__ dst){
  int v = blockIdx.x * 256 + threadIdx.x;
  const bool valid = (v < NV);
  const int vs = valid ? v : 0;
  const int bb = blockIdx.y * 256;
  float er[64];
  #pragma unroll
  for (int q = 0; q < 16; ++q){
    float4 tq = *(const float4*)(emb + (size_t)vs * 64 + q*4);
    er[q*4+0] = tq.x; er[q*4+1] = tq.y; er[q*4+2] = tq.z; er[q*4+3] = tq.w;
  }
  for (int b = bb; b < bb + 256; ++b){
    const float* ob = outv + b*64;   // wave-uniform -> scalar loads
    float a0 = 0.f, a1 = 0.f;
    #pragma unroll
    for (int e = 0; e < 64; e += 2){
      a0 = fmaf(ob[e],   er[e],   a0);
      a1 = fmaf(ob[e+1], er[e+1], a1);
    }
    if (valid) dst[(size_t)b * NV + v] = a0 + a1;
  }
}

extern "C" void kernel_launch(void* const* d_in, const int* in_sizes, int n_in,
                              void* d_out, int out_size, void* d_ws, size_t ws_size,
                              hipStream_t stream){
  const int*   inp  = (const int*)  d_in[0];
  const float* emb  = (const float*)d_in[1];
  const float* kern = (const float*)d_in[2];
  const float* rec  = (const float*)d_in[3];
  const float* bias = (const float*)d_in[4];
  const float* dw   = (const float*)d_in[5];
  const float* db   = (const float*)d_in[6];
  float* dst = (float*)d_out;
  char* ws = (char*)d_ws;

  unsigned short*     rb    = (unsigned short*)    (ws);            // 524288 B
  unsigned short*     kbf   = (unsigned short*)    (ws + 524288);   // 131072 B
  int*                tokT  = (int*)               (ws + 655360);   // 819200 B
  unsigned long long* maskP = (unsigned long long*)(ws + 1474560);  // 32768 B
  float*              hbuf  = (float*)             (ws + 1507328);  // 1048576 B
  float*              obuf  = (float*)             (ws + 2555904);  // 262144 B
  char*               wsxp  = (char*)              (ws + 2818048);  // 13107200 B

  const int SMEM_BYTES = 147456;
  hipFuncSetAttribute((const void*)lstm_kernel,
                      hipFuncAttributeMaxDynamicSharedMemorySize, SMEM_BYTES);

  prep_kernel  <<<1024, 256, 0, stream>>>(inp, kern, rec, rb, kbf, tokT, maskP);
  xproj_kernel <<<12800, 256, 0, stream>>>(emb, bias, kbf, tokT, dst, wsxp);
  lstm_kernel  <<<64, 1024, SMEM_BYTES, stream>>>(rb, maskP, dst, wsxp, hbuf);
  dense_kernel <<<256, 256, 0, stream>>>(hbuf, dw, db, obuf);
  logits_kernel<<<dim3(391, 4), 256, 0, stream>>>(obuf, emb, dst);
  (void)in_sizes; (void)n_in; (void)out_size; (void)ws_size;
}